// Round 9
// baseline (95.485 us; speedup 1.0000x reference)
//
#include <hip/hip_runtime.h>
#include <hip/hip_bf16.h>
#include <math.h>

// Problem constants (from the reference)
#define NALT      8
#define BDIM      8
#define CDIM      4
#define RDIM      512
#define OUT_HALF  (BDIM * CDIM * RDIM * NALT)   // 131072 floats
#define OUT_TOTAL (2 * OUT_HALF)                // 262144 floats [MC | SC]

#define NBUCKET   32          // bucket = b*4+c
#define BLK_ATOMS 1024        // atoms per block (256 thr x AITER)
#define AITER     4
#define NWAVE     4           // 256 threads / 64
#define LSLOTS    8192        // accum LDS tile: bb(2)*r(512)*alt(8) f32 = 32 KiB

// ws layout (runtime offsets, 256B-aligned):
//   PW   u32 [nblocks][NWAVE][32]  absolute staging base per (block,wave,bucket)
//   hdr  u16 [nblocks][64]         (0..32 = exclusive bucket offsets in block)
//   lidx u16 [nblocks][1024]
//   vals uint4[nblocks][1024]
//   partial f32 [NBUCKET*nsplit][LSLOTS]

__device__ __forceinline__ unsigned int pack_bf16_2(float a, float b) {
    unsigned int ua = __float_as_uint(a);
    unsigned int ub = __float_as_uint(b);
    ua = (ua + 0x7fffu + ((ua >> 16) & 1u)) >> 16;   // round-to-nearest-even
    ub = (ub + 0x7fffu + ((ub >> 16) & 1u)) >> 16;
    return ua | (ub << 16);
}

// K1: desc-only. Per-(wave,bucket) histogram -> scan -> absolute staging bases.
__global__ void __launch_bounds__(256) vdw_count_kernel(
    const int4*   __restrict__ desc,
    unsigned int* __restrict__ PW,     // [nblocks][NWAVE][32]
    unsigned short* __restrict__ hdr,  // [nblocks][64]
    int n)
{
    __shared__ unsigned int cw[NWAVE][NBUCKET];
    __shared__ unsigned int base[NBUCKET + 1];
    const int tid = threadIdx.x;
    const int w   = tid >> 6;
    if (tid < NWAVE * NBUCKET) cw[tid >> 5][tid & 31] = 0;
    __syncthreads();

    const int a0 = blockIdx.x * BLK_ATOMS;
    #pragma unroll
    for (int it = 0; it < AITER; ++it) {
        const int a = a0 + it * 256 + tid;
        if (a < n) {
            const int4 d = desc[a];
            if (d.w != -1) atomicAdd(&cw[w][d.y * CDIM + d.z], 1);
        }
    }
    __syncthreads();

    if (tid < NBUCKET) {
        unsigned int s = 0;
        unsigned int pref[NWAVE];
        #pragma unroll
        for (int ww = 0; ww < NWAVE; ++ww) { pref[ww] = s; s += cw[ww][tid]; }
        base[tid] = s;                       // total for this bucket (temporarily)
        #pragma unroll
        for (int ww = 0; ww < NWAVE; ++ww) cw[ww][tid] = pref[ww];
    }
    __syncthreads();
    if (tid == 0) {
        unsigned int run = 0;
        #pragma unroll
        for (int j = 0; j < NBUCKET; ++j) { const unsigned int t = base[j]; base[j] = run; run += t; }
        base[NBUCKET] = run;
    }
    __syncthreads();

    if (tid < NBUCKET) {
        #pragma unroll
        for (int ww = 0; ww < NWAVE; ++ww)
            PW[(size_t)blockIdx.x * (NWAVE * NBUCKET) + ww * NBUCKET + tid] =
                base[tid] + cw[ww][tid];
    }
    if (tid <= NBUCKET) hdr[blockIdx.x * 64 + tid] = (unsigned short)base[tid];
}

// K2: compact, ZERO barriers before copy-out. All loads issue up front;
// staging position = PW (precomputed) + per-wave LDS running rank.
__global__ void __launch_bounds__(256) vdw_compact_kernel(
    const int4*   __restrict__ desc,
    const int4*   __restrict__ mask,
    const float4* __restrict__ facc,
    const float*  __restrict__ props,
    const float*  __restrict__ weight,
    const unsigned int* __restrict__ PW,
    unsigned short* __restrict__ lidxArr,  // [nblocks][1024]
    uint4*        __restrict__ valArr,     // [nblocks][1024]
    int n)
{
    __shared__ unsigned short s_lidx[BLK_ATOMS];
    __shared__ uint4          s_val[BLK_ATOMS];
    __shared__ unsigned int   cw[NWAVE][NBUCKET];

    const int tid  = threadIdx.x;
    const int w    = tid >> 6;
    const int lane = tid & 63;
    // wave-local zero (wave-lockstep; LDS pipe is in-order per wave -> no barrier)
    if (lane < NBUCKET) cw[w][lane] = 0;

    const float scale = (1.0f - tanhf(weight[0])) * 0.3f;
    const int a0 = blockIdx.x * BLK_ATOMS;
    const unsigned int* myPW = PW + (size_t)blockIdx.x * (NWAVE * NBUCKET) + w * NBUCKET;

    // ---- all loads issued unconditionally up front (max MLP, no phases) ----
    int4   d_[AITER];
    float4 f0_[AITER], f1_[AITER];
    int4   m0_[AITER], m1_[AITER];
    bool   ok[AITER];
    #pragma unroll
    for (int it = 0; it < AITER; ++it) {
        const int a  = a0 + it * 256 + tid;
        ok[it] = (a < n);
        const int aa = ok[it] ? a : (n - 1);
        d_[it]  = desc[aa];
        f0_[it] = facc[aa * 2 + 0];
        f1_[it] = facc[aa * 2 + 1];
        m0_[it] = mask[aa * 2 + 0];
        m1_[it] = mask[aa * 2 + 1];
    }

    // ---- compute + stage (no block barrier) ----
    #pragma unroll
    for (int it = 0; it < AITER; ++it) {
        const int4 d = d_[it];
        if (!ok[it] || d.w == -1) continue;
        const int bkt  = d.y * CDIM + d.z;
        const float vs = props[d.x * 8] * scale;
        const int lidx = ((d.x < 4) ? 0 : 4096) + d.w * 8;

        const float4 f0 = f0_[it], f1 = f1_[it];
        const int4   m0 = m0_[it], m1 = m1_[it];
        const float v0 = m0.x ? vs * fmaxf(f0.x, 0.0f) : 0.0f;
        const float v1 = m0.y ? vs * fmaxf(f0.y, 0.0f) : 0.0f;
        const float v2 = m0.z ? vs * fmaxf(f0.z, 0.0f) : 0.0f;
        const float v3 = m0.w ? vs * fmaxf(f0.w, 0.0f) : 0.0f;
        const float v4 = m1.x ? vs * fmaxf(f1.x, 0.0f) : 0.0f;
        const float v5 = m1.y ? vs * fmaxf(f1.y, 0.0f) : 0.0f;
        const float v6 = m1.z ? vs * fmaxf(f1.z, 0.0f) : 0.0f;
        const float v7 = m1.w ? vs * fmaxf(f1.w, 0.0f) : 0.0f;

        const unsigned int rank = atomicAdd(&cw[w][bkt], 1u);
        const unsigned int pos  = myPW[bkt] + rank;
        s_lidx[pos] = (unsigned short)lidx;
        s_val[pos]  = make_uint4(pack_bf16_2(v0, v1), pack_bf16_2(v2, v3),
                                 pack_bf16_2(v4, v5), pack_bf16_2(v6, v7));
    }
    __syncthreads();   // only barrier: before coalesced copy-out (loads all consumed)

    unsigned int* ldst = (unsigned int*)(lidxArr + (size_t)blockIdx.x * BLK_ATOMS);
    const unsigned int* lsrc = (const unsigned int*)s_lidx;
    #pragma unroll
    for (int k = 0; k < BLK_ATOMS / 2 / 256; ++k)
        ldst[k * 256 + tid] = lsrc[k * 256 + tid];

    uint4* vdst = valArr + (size_t)blockIdx.x * BLK_ATOMS;
    #pragma unroll
    for (int k = 0; k < BLK_ATOMS / 256; ++k)
        vdst[k * 256 + tid] = s_val[k * 256 + tid];
}

// K3: accum. Block (bucket, split) walks its source-block range's bucket runs
// (contiguous bursts) into a 32 KiB LDS tile; writes dense partial.
__global__ void __launch_bounds__(256) vdw_accum_kernel(
    const unsigned short* __restrict__ hdrArr,
    const unsigned short* __restrict__ lidxArr,
    const uint4*          __restrict__ valArr,
    float*                __restrict__ partial,
    int nblocks, int nsplit)
{
    __shared__ float acc[LSLOTS];
    const int tid = threadIdx.x;
    for (int k = tid; k < LSLOTS; k += 256) acc[k] = 0.0f;
    __syncthreads();

    const int bucket = blockIdx.x / nsplit;
    const int split  = blockIdx.x % nsplit;
    const int per = (nblocks + nsplit - 1) / nsplit;
    const int b0  = split * per;
    const int b1  = (b0 + per < nblocks) ? (b0 + per) : nblocks;

    const int g    = tid >> 5;    // 8 groups of 32 lanes
    const int lane = tid & 31;

    for (int blk = b0 + g; blk < b1; blk += 8) {
        const int start = hdrArr[blk * 64 + bucket];
        const int end   = hdrArr[blk * 64 + bucket + 1];
        const unsigned short* la = lidxArr + (size_t)blk * BLK_ATOMS;
        const uint4*          va = valArr  + (size_t)blk * BLK_ATOMS;
        for (int rec = start + lane; rec < end; rec += 32) {
            const int   l = la[rec];
            const uint4 v = va[rec];
            float t;
            t = __uint_as_float(v.x << 16);          if (t != 0.0f) atomicAdd(&acc[l + 0], t);
            t = __uint_as_float(v.x & 0xffff0000u);  if (t != 0.0f) atomicAdd(&acc[l + 1], t);
            t = __uint_as_float(v.y << 16);          if (t != 0.0f) atomicAdd(&acc[l + 2], t);
            t = __uint_as_float(v.y & 0xffff0000u);  if (t != 0.0f) atomicAdd(&acc[l + 3], t);
            t = __uint_as_float(v.z << 16);          if (t != 0.0f) atomicAdd(&acc[l + 4], t);
            t = __uint_as_float(v.z & 0xffff0000u);  if (t != 0.0f) atomicAdd(&acc[l + 5], t);
            t = __uint_as_float(v.w << 16);          if (t != 0.0f) atomicAdd(&acc[l + 6], t);
            t = __uint_as_float(v.w & 0xffff0000u);  if (t != 0.0f) atomicAdd(&acc[l + 7], t);
        }
    }
    __syncthreads();

    float* dst = partial + (size_t)blockIdx.x * LSLOTS;
    for (int k = tid; k < LSLOTS; k += 256) dst[k] = acc[k];
}

// K4: out[idx] = sum over splits of matching partial. Writes every element.
__global__ void __launch_bounds__(256) vdw_merge_kernel(
    const float* __restrict__ partial,
    float*       __restrict__ out,
    int nsplit)
{
    const int idx = blockIdx.x * 256 + threadIdx.x;
    if (idx >= OUT_TOTAL) return;
    const int bb     = idx >> 17;
    const int b      = (idx >> 14) & 7;
    const int c      = (idx >> 12) & 3;
    const int lidx   = bb * 4096 + (idx & 4095);   // r*8+alt
    const int bucket = b * CDIM + c;
    const float* p = partial + ((size_t)bucket * nsplit) * LSLOTS + lidx;
    float s = 0.0f;
    for (int sp = 0; sp < nsplit; ++sp)
        s += p[(size_t)sp * LSLOTS];
    out[idx] = s;
}

// Fallback (small ws): direct global atomics into d_out.
__global__ void __launch_bounds__(256) vdw_atomic_kernel(
    const int*   __restrict__ desc,
    const int*   __restrict__ mask,
    const float* __restrict__ facc,
    const float* __restrict__ props,
    const float* __restrict__ weight,
    float*       __restrict__ out,
    int n)
{
    const int i = blockIdx.x * blockDim.x + threadIdx.x;
    if (i >= n) return;
    const float scale = (1.0f - tanhf(weight[0])) * 0.3f;
    const int4 d = reinterpret_cast<const int4*>(desc)[i];
    if (d.w == -1) return;
    const float vs = props[d.x * 8 + 0] * scale;
    const int   bb = (d.x >= 0 && d.x <= 3) ? 0 : 1;
    float* base = out + bb * OUT_HALF + (((d.y * CDIM + d.z) * RDIM + d.w) * NALT);
    const float4 f0 = reinterpret_cast<const float4*>(facc)[i * 2 + 0];
    const float4 f1 = reinterpret_cast<const float4*>(facc)[i * 2 + 1];
    const int4   m0 = reinterpret_cast<const int4*>(mask)[i * 2 + 0];
    const int4   m1 = reinterpret_cast<const int4*>(mask)[i * 2 + 1];
    if (m0.x) atomicAdd(base + 0, vs * fmaxf(f0.x, 0.0f));
    if (m0.y) atomicAdd(base + 1, vs * fmaxf(f0.y, 0.0f));
    if (m0.z) atomicAdd(base + 2, vs * fmaxf(f0.z, 0.0f));
    if (m0.w) atomicAdd(base + 3, vs * fmaxf(f0.w, 0.0f));
    if (m1.x) atomicAdd(base + 4, vs * fmaxf(f1.x, 0.0f));
    if (m1.y) atomicAdd(base + 5, vs * fmaxf(f1.y, 0.0f));
    if (m1.z) atomicAdd(base + 6, vs * fmaxf(f1.z, 0.0f));
    if (m1.w) atomicAdd(base + 7, vs * fmaxf(f1.w, 0.0f));
}

extern "C" void kernel_launch(void* const* d_in, const int* in_sizes, int n_in,
                              void* d_out, int out_size, void* d_ws, size_t ws_size,
                              hipStream_t stream)
{
    // Inputs per setup_inputs():
    // 0: coords (unused)  1: atom_description (N,4) int32
    // 2: alternativeMask (N,8) int32  3: facc (N,8) f32
    // 4: atom_Properties (500,8) f32  5: weight (1,) f32
    const int*   desc   = (const int*)d_in[1];
    const int*   mask   = (const int*)d_in[2];
    const float* facc   = (const float*)d_in[3];
    const float* props  = (const float*)d_in[4];
    const float* weight = (const float*)d_in[5];
    float*       out    = (float*)d_out;

    const int n       = in_sizes[1] / 4;
    const int nblocks = (n + BLK_ATOMS - 1) / BLK_ATOMS;

    auto align256 = [](size_t x) { return (x + 255) & ~(size_t)255; };
    const size_t off_pw   = 0;
    const size_t off_hdr  = align256(off_pw   + (size_t)nblocks * NWAVE * NBUCKET * 4);
    const size_t off_lidx = align256(off_hdr  + (size_t)nblocks * 64 * 2);
    const size_t off_val  = align256(off_lidx + (size_t)nblocks * BLK_ATOMS * 2);
    const size_t off_part = align256(off_val  + (size_t)nblocks * BLK_ATOMS * 16);

    int nsplit = 0;
    for (int cand = 16; cand >= 1; cand >>= 1) {
        const size_t need = off_part +
            (size_t)NBUCKET * cand * LSLOTS * sizeof(float);
        if (need <= ws_size) { nsplit = cand; break; }
    }

    if (nsplit >= 1) {
        char* ws = (char*)d_ws;
        unsigned int*   PWarr   = (unsigned int*)(ws + off_pw);
        unsigned short* hdrArr  = (unsigned short*)(ws + off_hdr);
        unsigned short* lidxArr = (unsigned short*)(ws + off_lidx);
        uint4*          valArr  = (uint4*)(ws + off_val);
        float*          part    = (float*)(ws + off_part);

        vdw_count_kernel<<<nblocks, 256, 0, stream>>>(
            (const int4*)desc, PWarr, hdrArr, n);

        vdw_compact_kernel<<<nblocks, 256, 0, stream>>>(
            (const int4*)desc, (const int4*)mask, (const float4*)facc,
            props, weight, PWarr, lidxArr, valArr, n);

        vdw_accum_kernel<<<NBUCKET * nsplit, 256, 0, stream>>>(
            hdrArr, lidxArr, valArr, part, nblocks, nsplit);

        vdw_merge_kernel<<<(OUT_TOTAL + 255) / 256, 256, 0, stream>>>(
            part, out, nsplit);
    } else {
        hipMemsetAsync(d_out, 0, (size_t)out_size * sizeof(float), stream);
        vdw_atomic_kernel<<<(n + 255) / 256, 256, 0, stream>>>(
            desc, mask, facc, props, weight, out, n);
    }
}